// Round 2
// baseline (364.800 us; speedup 1.0000x reference)
//
#include <hip/hip_runtime.h>
#include <math.h>

#define BB   2
#define CFI  32
#define NN   36864          // 192*192
#define NUMM 16

// ---- workspace float-offset layout -----------------------------------------
#define OFF_W1A   0        // [32][32] W1 cols 0..31  (folded with inv1)
#define OFF_W1B   1024     // [32][32] W1 cols 32..63 (folded)
#define OFF_W1P   2048     // [32]     W1 col 64 (Pf term, folded)
#define OFF_W1O0  2080     // [32]     W1 col 65 (folded)
#define OFF_W1O1  2112     // [32]     W1 col 66 (folded)
#define OFF_BETA1 2144     // [32]
#define OFF_W2    2176     // [32][32] folded
#define OFF_BETA2 3200
#define OFF_W3    3232
#define OFF_BETA3 4256
#define OFF_W4    4288
#define OFF_BETA4 5312
#define OFF_WCA   5344     // [32] Wc row 0 (alpha)
#define OFF_WCB   5376     // [32] Wc row 1 (beta)
#define OFF_WCO   5408     // [32] Wc row 2 (omega)
#define OFF_BC    5440     // [3]
#define OFF_Y     6144     // [B*N][32] point-major, beta1 folded in
#define OFF_Z     (OFF_Y + BB*NN*CFI)   // [B*N][32] point-major, Pf term folded in

static __device__ __forceinline__ float gelu_exact(float x) {
    return 0.5f * x * (1.0f + erff(x * 0.70710678118654752f));
}

// ---- kernel 0: fold BN into weights, write folded params to ws -------------
__global__ void fold_kernel(
    const float* __restrict__ W1, const float* __restrict__ g1, const float* __restrict__ b1, const float* __restrict__ m1, const float* __restrict__ v1,
    const float* __restrict__ W2, const float* __restrict__ g2, const float* __restrict__ b2, const float* __restrict__ m2, const float* __restrict__ v2,
    const float* __restrict__ W3, const float* __restrict__ g3, const float* __restrict__ b3, const float* __restrict__ m3, const float* __restrict__ v3,
    const float* __restrict__ W4, const float* __restrict__ g4, const float* __restrict__ b4, const float* __restrict__ m4, const float* __restrict__ v4,
    const float* __restrict__ Wc, const float* __restrict__ bc,
    float* ws)
{
    const int t = threadIdx.x;
    for (int i = t; i < 32 * 67; i += 256) {
        int o = i / 67, c = i - o * 67;
        float inv = g1[o] * rsqrtf(v1[o] + 1e-5f);
        float w = W1[i] * inv;
        if (c < 32)       ws[OFF_W1A + o * 32 + c] = w;
        else if (c < 64)  ws[OFF_W1B + o * 32 + (c - 32)] = w;
        else if (c == 64) ws[OFF_W1P + o] = w;
        else if (c == 65) ws[OFF_W1O0 + o] = w;
        else              ws[OFF_W1O1 + o] = w;
    }
    for (int i = t; i < 1024; i += 256) {
        int o = i >> 5;
        ws[OFF_W2 + i] = W2[i] * (g2[o] * rsqrtf(v2[o] + 1e-5f));
        ws[OFF_W3 + i] = W3[i] * (g3[o] * rsqrtf(v3[o] + 1e-5f));
        ws[OFF_W4 + i] = W4[i] * (g4[o] * rsqrtf(v4[o] + 1e-5f));
    }
    if (t < 32) {
        float i1 = g1[t] * rsqrtf(v1[t] + 1e-5f);
        float i2 = g2[t] * rsqrtf(v2[t] + 1e-5f);
        float i3 = g3[t] * rsqrtf(v3[t] + 1e-5f);
        float i4 = g4[t] * rsqrtf(v4[t] + 1e-5f);
        ws[OFF_BETA1 + t] = b1[t] - m1[t] * i1;
        ws[OFF_BETA2 + t] = b2[t] - m2[t] * i2;
        ws[OFF_BETA3 + t] = b3[t] - m3[t] * i3;
        ws[OFF_BETA4 + t] = b4[t] - m4[t] * i4;
        ws[OFF_WCA + t] = Wc[t];
        ws[OFF_WCB + t] = Wc[32 + t];
        ws[OFF_WCO + t] = Wc[64 + t];
    }
    if (t < 3) ws[OFF_BC + t] = bc[t];
}

// ---- kernel A: per-point Y/Z precompute (layer-1 split) --------------------
// Y[b,n,o] = beta1[o] + sum_c W1f[o][c]    * If[b,c,n]
// Z[b,n,o] =            sum_c W1f[o][32+c] * If[b,c,n] + W1f[o][64]*Pf[b,n]
__launch_bounds__(256)
__global__ void yz_kernel(const float* __restrict__ If, const float* __restrict__ Pf,
                          float* ws)
{
    const int t = blockIdx.x * 256 + threadIdx.x;   // 0 .. B*N-1
    if (t >= BB * NN) return;
    const int b = t / NN, n = t - b * NN;
    const float* ifp = If + (size_t)b * CFI * NN + n;
    const float* w = ws;

    float accY[32], accZ[32];
#pragma unroll
    for (int o = 0; o < 32; o++) { accY[o] = w[OFF_BETA1 + o]; accZ[o] = 0.0f; }

#pragma unroll
    for (int c = 0; c < 32; c++) {
        float v = ifp[(size_t)c * NN];
#pragma unroll
        for (int o = 0; o < 32; o++) {
            accY[o] = fmaf(w[OFF_W1A + o * 32 + c], v, accY[o]);
            accZ[o] = fmaf(w[OFF_W1B + o * 32 + c], v, accZ[o]);
        }
    }
    float pf = Pf[t];
#pragma unroll
    for (int o = 0; o < 32; o++) accZ[o] = fmaf(w[OFF_W1P + o], pf, accZ[o]);

    float4* yp = (float4*)(ws + OFF_Y + (size_t)t * 32);
    float4* zp = (float4*)(ws + OFF_Z + (size_t)t * 32);
#pragma unroll
    for (int i = 0; i < 8; i++) {
        yp[i] = make_float4(accY[4 * i], accY[4 * i + 1], accY[4 * i + 2], accY[4 * i + 3]);
        zp[i] = make_float4(accZ[4 * i], accZ[4 * i + 1], accZ[4 * i + 2], accZ[4 * i + 3]);
    }
}

// ---- kernel B: main fused MLP + softmax reduction --------------------------
// one thread per (b, m, n); lanes 0..15 of each 16-lane group = m 0..15
__launch_bounds__(256)
__global__ void main_kernel(const float* __restrict__ Pf, const float* __restrict__ Of,
                            const int* __restrict__ args,
                            const float* __restrict__ ws, float* __restrict__ out)
{
    const int t = blockIdx.x * 256 + threadIdx.x;   // 0 .. B*NUM*N-1
    const int m = t & 15;
    const int q = t >> 4;                            // 0 .. B*N-1
    const int b = q / NN, n = q - b * NN;

    const int   a   = args[((b * NUMM) + m) * NN + n];
    const float of0 = Of[(((b * 2 + 0) * NUMM) + m) * NN + n];
    const float of1 = Of[(((b * 2 + 1) * NUMM) + m) * NN + n];
    const float pfg = Pf[b * NN + a];

    const float4* yp = (const float4*)(ws + OFF_Y + (size_t)q * 32);
    const float4* zp = (const float4*)(ws + OFF_Z + ((size_t)b * NN + a) * 32);

    float h1[32];
#pragma unroll
    for (int i = 0; i < 8; i++) {
        float4 y = yp[i], z = zp[i];
        h1[4 * i + 0] = y.x + z.x;
        h1[4 * i + 1] = y.y + z.y;
        h1[4 * i + 2] = y.z + z.z;
        h1[4 * i + 3] = y.w + z.w;
    }
#pragma unroll
    for (int o = 0; o < 32; o++) {
        float pre = h1[o];
        pre = fmaf(of0, ws[OFF_W1O0 + o], pre);
        pre = fmaf(of1, ws[OFF_W1O1 + o], pre);
        h1[o] = gelu_exact(pre);
    }

    float h2[32];
#pragma unroll
    for (int o = 0; o < 32; o++) {
        float acc = ws[OFF_BETA2 + o];
#pragma unroll
        for (int c = 0; c < 32; c++) acc = fmaf(ws[OFF_W2 + o * 32 + c], h1[c], acc);
        h2[o] = gelu_exact(acc);
    }

    float l3[32];
#pragma unroll
    for (int o = 0; o < 32; o++) {
        float acc = ws[OFF_BETA3 + o];
#pragma unroll
        for (int c = 0; c < 32; c++) acc = fmaf(ws[OFF_W3 + o * 32 + c], h2[c], acc);
        l3[o] = gelu_exact(acc);
    }

    float alpha = ws[OFF_BC + 0], beta_ = ws[OFF_BC + 1], omega = ws[OFF_BC + 2];
#pragma unroll
    for (int o = 0; o < 32; o++) {
        float acc = ws[OFF_BETA4 + o];
#pragma unroll
        for (int c = 0; c < 32; c++) acc = fmaf(ws[OFF_W4 + o * 32 + c], l3[c], acc);
        float xf = gelu_exact(h2[o] + acc);
        alpha = fmaf(ws[OFF_WCA + o], xf, alpha);
        beta_ = fmaf(ws[OFF_WCB + o], xf, beta_);
        omega = fmaf(ws[OFF_WCO + o], xf, omega);
    }

    const float val = fmaf(alpha + 1.0f, pfg, beta_);

    // softmax over m within each 16-lane group (lane bits 0..3)
    float mx = omega;
#pragma unroll
    for (int s = 1; s < 16; s <<= 1) mx = fmaxf(mx, __shfl_xor(mx, s, 64));
    const float e = __expf(omega - mx);
    float S = e, T = val * e;
#pragma unroll
    for (int s = 1; s < 16; s <<= 1) {
        S += __shfl_xor(S, s, 64);
        T += __shfl_xor(T, s, 64);
    }
    if (m == 0) out[q] = T / S;
}

// ---- launcher ---------------------------------------------------------------
extern "C" void kernel_launch(void* const* d_in, const int* in_sizes, int n_in,
                              void* d_out, int out_size, void* d_ws, size_t ws_size,
                              hipStream_t stream) {
    const float* If    = (const float*)d_in[0];
    const float* Pf    = (const float*)d_in[1];
    const float* Of    = (const float*)d_in[2];
    const int*   args  = (const int*)d_in[3];
    const float* W1    = (const float*)d_in[4];
    const float* g1    = (const float*)d_in[5];
    const float* b1    = (const float*)d_in[6];
    const float* m1    = (const float*)d_in[7];
    const float* v1    = (const float*)d_in[8];
    const float* W2    = (const float*)d_in[9];
    const float* g2    = (const float*)d_in[10];
    const float* b2    = (const float*)d_in[11];
    const float* m2    = (const float*)d_in[12];
    const float* v2    = (const float*)d_in[13];
    const float* W3    = (const float*)d_in[14];
    const float* g3    = (const float*)d_in[15];
    const float* b3    = (const float*)d_in[16];
    const float* m3    = (const float*)d_in[17];
    const float* v3    = (const float*)d_in[18];
    const float* W4    = (const float*)d_in[19];
    const float* g4    = (const float*)d_in[20];
    const float* b4    = (const float*)d_in[21];
    const float* m4    = (const float*)d_in[22];
    const float* v4    = (const float*)d_in[23];
    const float* Wc    = (const float*)d_in[24];
    const float* bc    = (const float*)d_in[25];

    float* ws = (float*)d_ws;
    float* out = (float*)d_out;

    fold_kernel<<<1, 256, 0, stream>>>(W1, g1, b1, m1, v1,
                                       W2, g2, b2, m2, v2,
                                       W3, g3, b3, m3, v3,
                                       W4, g4, b4, m4, v4,
                                       Wc, bc, ws);

    yz_kernel<<<(BB * NN) / 256, 256, 0, stream>>>(If, Pf, ws);

    main_kernel<<<(BB * NUMM * NN) / 256, 256, 0, stream>>>(Pf, Of, args, ws, out);
}

// Round 3
// 320.836 us; speedup vs baseline: 1.1370x; 1.1370x over previous
//
#include <hip/hip_runtime.h>
#include <math.h>

#define BB   2
#define CFI  32
#define NN   36864          // 192*192
#define NUMM 16

// ---- workspace float-offset layout -----------------------------------------
#define OFF_W1A   0        // [32][32] W1 cols 0..31  (folded with inv1)
#define OFF_W1B   1024     // [32][32] W1 cols 32..63 (folded)
#define OFF_W1P   2048     // [32]     W1 col 64 (Pf term, folded)
#define OFF_W1O0  2080     // [32]     W1 col 65 (folded)
#define OFF_W1O1  2112     // [32]     W1 col 66 (folded)
#define OFF_BETA1 2144     // [32]
#define OFF_W2    2176     // [32][32] folded
#define OFF_BETA2 3200
#define OFF_W3    3232
#define OFF_BETA3 4256
#define OFF_W4    4288
#define OFF_BETA4 5312
#define OFF_WCA   5344     // [32] Wc row 0 (alpha)
#define OFF_WCB   5376     // [32] Wc row 1 (beta)
#define OFF_WCO   5408     // [32] Wc row 2 (omega)
#define OFF_BC    5440     // [3]
#define OFF_Y     6144     // [B*N][32] point-major, beta1 folded in
#define OFF_Z     (OFF_Y + BB*NN*CFI)   // [B*N][32] point-major, Pf term folded in

// Branch-free erf-based gelu. A&S 7.1.26: |eps_abs(erf)| <= 1.5e-7.
// ~16 VALU ops, no divergence (vs ocml erff: branchy, wave-divergent).
static __device__ __forceinline__ float gelu_fast(float x) {
    const float s  = x * 0.70710678118654752f;      // x / sqrt(2)
    const float ax = fabsf(s);
    const float t  = __builtin_amdgcn_rcpf(fmaf(0.3275911f, ax, 1.0f));
    float p = fmaf(1.061405429f, t, -1.453152027f);
    p = fmaf(p, t, 1.421413741f);
    p = fmaf(p, t, -0.284496736f);
    p = fmaf(p, t, 0.254829592f);
    p = p * t;
    const float e  = __expf(-s * s);
    float er = fmaf(-p, e, 1.0f);                   // erf(|s|)
    er = copysignf(er, s);
    return 0.5f * x * (1.0f + er);
}

// ---- kernel 0: fold BN into weights, write folded params to ws -------------
__global__ void fold_kernel(
    const float* __restrict__ W1, const float* __restrict__ g1, const float* __restrict__ b1, const float* __restrict__ m1, const float* __restrict__ v1,
    const float* __restrict__ W2, const float* __restrict__ g2, const float* __restrict__ b2, const float* __restrict__ m2, const float* __restrict__ v2,
    const float* __restrict__ W3, const float* __restrict__ g3, const float* __restrict__ b3, const float* __restrict__ m3, const float* __restrict__ v3,
    const float* __restrict__ W4, const float* __restrict__ g4, const float* __restrict__ b4, const float* __restrict__ m4, const float* __restrict__ v4,
    const float* __restrict__ Wc, const float* __restrict__ bc,
    float* ws)
{
    const int t = threadIdx.x;
    for (int i = t; i < 32 * 67; i += 256) {
        int o = i / 67, c = i - o * 67;
        float inv = g1[o] * rsqrtf(v1[o] + 1e-5f);
        float w = W1[i] * inv;
        if (c < 32)       ws[OFF_W1A + o * 32 + c] = w;
        else if (c < 64)  ws[OFF_W1B + o * 32 + (c - 32)] = w;
        else if (c == 64) ws[OFF_W1P + o] = w;
        else if (c == 65) ws[OFF_W1O0 + o] = w;
        else              ws[OFF_W1O1 + o] = w;
    }
    for (int i = t; i < 1024; i += 256) {
        int o = i >> 5;
        ws[OFF_W2 + i] = W2[i] * (g2[o] * rsqrtf(v2[o] + 1e-5f));
        ws[OFF_W3 + i] = W3[i] * (g3[o] * rsqrtf(v3[o] + 1e-5f));
        ws[OFF_W4 + i] = W4[i] * (g4[o] * rsqrtf(v4[o] + 1e-5f));
    }
    if (t < 32) {
        float i1 = g1[t] * rsqrtf(v1[t] + 1e-5f);
        float i2 = g2[t] * rsqrtf(v2[t] + 1e-5f);
        float i3 = g3[t] * rsqrtf(v3[t] + 1e-5f);
        float i4 = g4[t] * rsqrtf(v4[t] + 1e-5f);
        ws[OFF_BETA1 + t] = b1[t] - m1[t] * i1;
        ws[OFF_BETA2 + t] = b2[t] - m2[t] * i2;
        ws[OFF_BETA3 + t] = b3[t] - m3[t] * i3;
        ws[OFF_BETA4 + t] = b4[t] - m4[t] * i4;
        ws[OFF_WCA + t] = Wc[t];
        ws[OFF_WCB + t] = Wc[32 + t];
        ws[OFF_WCO + t] = Wc[64 + t];
    }
    if (t < 3) ws[OFF_BC + t] = bc[t];
}

// ---- kernel A: per-point Y/Z precompute (layer-1 split), 4 threads/point ---
// Channel-slice r lives in HIGH blockIdx bits so weight addresses stay
// wave-uniform (s_load eligible). 1152 blocks -> ~18 waves/CU.
#define YZ_SLICE_BLOCKS ((BB * NN) / 256)   // 288
__launch_bounds__(256)
__global__ void yz_kernel(const float* __restrict__ If, const float* __restrict__ Pf,
                          float* ws)
{
    const int r = blockIdx.x / YZ_SLICE_BLOCKS;              // 0..3 channel slice
    const int p = (blockIdx.x % YZ_SLICE_BLOCKS) * 256 + threadIdx.x; // 0..B*N-1
    const int b = p / NN, n = p - b * NN;
    const int o0 = r * 8;
    const float* ifp = If + (size_t)b * CFI * NN + n;
    const float* w = ws;

    float accY[8], accZ[8];
#pragma unroll
    for (int j = 0; j < 8; j++) { accY[j] = w[OFF_BETA1 + o0 + j]; accZ[j] = 0.0f; }

#pragma unroll
    for (int c = 0; c < 32; c++) {
        float v = ifp[(size_t)c * NN];
#pragma unroll
        for (int j = 0; j < 8; j++) {
            accY[j] = fmaf(w[OFF_W1A + (o0 + j) * 32 + c], v, accY[j]);
            accZ[j] = fmaf(w[OFF_W1B + (o0 + j) * 32 + c], v, accZ[j]);
        }
    }
    float pf = Pf[p];
#pragma unroll
    for (int j = 0; j < 8; j++) accZ[j] = fmaf(w[OFF_W1P + o0 + j], pf, accZ[j]);

    float4* yp = (float4*)(ws + OFF_Y + (size_t)p * 32 + o0);
    float4* zp = (float4*)(ws + OFF_Z + (size_t)p * 32 + o0);
    yp[0] = make_float4(accY[0], accY[1], accY[2], accY[3]);
    yp[1] = make_float4(accY[4], accY[5], accY[6], accY[7]);
    zp[0] = make_float4(accZ[0], accZ[1], accZ[2], accZ[3]);
    zp[1] = make_float4(accZ[4], accZ[5], accZ[6], accZ[7]);
}

// ---- kernel B: main fused MLP + softmax reduction --------------------------
// one thread per (b, m, n); lanes 0..15 of each 16-lane group = m 0..15
// __launch_bounds__(256,2): allow ~256 VGPR budget -> no scratch spills for
// h2[32]+l3[32]+head live set; 2 waves/EU suffices for independent-fma stream.
__launch_bounds__(256, 2)
__global__ void main_kernel(const float* __restrict__ Pf, const float* __restrict__ Of,
                            const int* __restrict__ args,
                            const float* __restrict__ ws, float* __restrict__ out)
{
    const int t = blockIdx.x * 256 + threadIdx.x;   // 0 .. B*NUM*N-1
    const int m = t & 15;
    const int q = t >> 4;                            // 0 .. B*N-1
    const int b = q / NN, n = q - b * NN;

    const int   a   = args[((b * NUMM) + m) * NN + n];
    const float of0 = Of[(((b * 2 + 0) * NUMM) + m) * NN + n];
    const float of1 = Of[(((b * 2 + 1) * NUMM) + m) * NN + n];
    const float pfg = Pf[b * NN + a];

    const float4* yp = (const float4*)(ws + OFF_Y + (size_t)q * 32);
    const float4* zp = (const float4*)(ws + OFF_Z + ((size_t)b * NN + a) * 32);

    float h1[32];
#pragma unroll
    for (int i = 0; i < 8; i++) {
        float4 y = yp[i], z = zp[i];
        h1[4 * i + 0] = y.x + z.x;
        h1[4 * i + 1] = y.y + z.y;
        h1[4 * i + 2] = y.z + z.z;
        h1[4 * i + 3] = y.w + z.w;
    }
#pragma unroll
    for (int o = 0; o < 32; o++) {
        float pre = h1[o];
        pre = fmaf(of0, ws[OFF_W1O0 + o], pre);
        pre = fmaf(of1, ws[OFF_W1O1 + o], pre);
        h1[o] = gelu_fast(pre);
    }

    float h2[32];
#pragma unroll
    for (int o = 0; o < 32; o++) {
        float acc = ws[OFF_BETA2 + o];
#pragma unroll
        for (int c = 0; c < 32; c++) acc = fmaf(ws[OFF_W2 + o * 32 + c], h1[c], acc);
        h2[o] = gelu_fast(acc);
    }

    float l3[32];
#pragma unroll
    for (int o = 0; o < 32; o++) {
        float acc = ws[OFF_BETA3 + o];
#pragma unroll
        for (int c = 0; c < 32; c++) acc = fmaf(ws[OFF_W3 + o * 32 + c], h2[c], acc);
        l3[o] = gelu_fast(acc);
    }

    float alpha = ws[OFF_BC + 0], beta_ = ws[OFF_BC + 1], omega = ws[OFF_BC + 2];
#pragma unroll
    for (int o = 0; o < 32; o++) {
        float acc = ws[OFF_BETA4 + o];
#pragma unroll
        for (int c = 0; c < 32; c++) acc = fmaf(ws[OFF_W4 + o * 32 + c], l3[c], acc);
        float xf = gelu_fast(h2[o] + acc);
        alpha = fmaf(ws[OFF_WCA + o], xf, alpha);
        beta_ = fmaf(ws[OFF_WCB + o], xf, beta_);
        omega = fmaf(ws[OFF_WCO + o], xf, omega);
    }

    const float val = fmaf(alpha + 1.0f, pfg, beta_);

    // softmax over m within each 16-lane group (lane bits 0..3)
    float mx = omega;
#pragma unroll
    for (int s = 1; s < 16; s <<= 1) mx = fmaxf(mx, __shfl_xor(mx, s, 64));
    const float e = __expf(omega - mx);
    float S = e, T = val * e;
#pragma unroll
    for (int s = 1; s < 16; s <<= 1) {
        S += __shfl_xor(S, s, 64);
        T += __shfl_xor(T, s, 64);
    }
    if (m == 0) out[q] = T / S;
}

// ---- launcher ---------------------------------------------------------------
extern "C" void kernel_launch(void* const* d_in, const int* in_sizes, int n_in,
                              void* d_out, int out_size, void* d_ws, size_t ws_size,
                              hipStream_t stream) {
    const float* If    = (const float*)d_in[0];
    const float* Pf    = (const float*)d_in[1];
    const float* Of    = (const float*)d_in[2];
    const int*   args  = (const int*)d_in[3];
    const float* W1    = (const float*)d_in[4];
    const float* g1    = (const float*)d_in[5];
    const float* b1    = (const float*)d_in[6];
    const float* m1    = (const float*)d_in[7];
    const float* v1    = (const float*)d_in[8];
    const float* W2    = (const float*)d_in[9];
    const float* g2    = (const float*)d_in[10];
    const float* b2    = (const float*)d_in[11];
    const float* m2    = (const float*)d_in[12];
    const float* v2    = (const float*)d_in[13];
    const float* W3    = (const float*)d_in[14];
    const float* g3    = (const float*)d_in[15];
    const float* b3    = (const float*)d_in[16];
    const float* m3    = (const float*)d_in[17];
    const float* v3    = (const float*)d_in[18];
    const float* W4    = (const float*)d_in[19];
    const float* g4    = (const float*)d_in[20];
    const float* b4    = (const float*)d_in[21];
    const float* m4    = (const float*)d_in[22];
    const float* v4    = (const float*)d_in[23];
    const float* Wc    = (const float*)d_in[24];
    const float* bc    = (const float*)d_in[25];

    float* ws = (float*)d_ws;
    float* out = (float*)d_out;

    fold_kernel<<<1, 256, 0, stream>>>(W1, g1, b1, m1, v1,
                                       W2, g2, b2, m2, v2,
                                       W3, g3, b3, m3, v3,
                                       W4, g4, b4, m4, v4,
                                       Wc, bc, ws);

    yz_kernel<<<YZ_SLICE_BLOCKS * 4, 256, 0, stream>>>(If, Pf, ws);

    main_kernel<<<(BB * NUMM * NN) / 256, 256, 0, stream>>>(Pf, Of, args, ws, out);
}